// Round 11
// baseline (925.961 us; speedup 1.0000x reference)
//
#include <hip/hip_runtime.h>
#include <hip/hip_bf16.h>
#include <hip/hip_cooperative_groups.h>
#include <math.h>

namespace cg = cooperative_groups;

#define NEG_ 16
#define PRED_ 5
#define EPS_ 1e-11f
#define LDW 18    // logit tile row stride (floats)
#define CTXW 264  // ctx row stride in shorts: 2-way bank aliasing only (free)
#define GRID 768  // 3 blocks/CU co-resident (launch_bounds(256,3))

typedef __attribute__((ext_vector_type(8))) short bf16x8;
typedef __attribute__((ext_vector_type(4))) float f32x4;

static __device__ __forceinline__ unsigned short f2bu(float f) {
  __hip_bfloat16 h = __float2bfloat16(f);
  return *(unsigned short*)&h;
}

// ws layout (bytes):
//   Zp bf16 [16384][256] : 0         rows q*64+b; rows<2048 (h<2) never touched
//   Cb bf16 [16384][256] : 8388608   rows>=14336 never touched
//   Wb bf16 [5][256][256]: 16777216
//   Yb bf16 [5][14336][256]: 17432576  rows>=Mk unused per k
//   Lk f32  [5][14336]   : 54132736  tails [Mk,14336) NEVER read -> no memset
// Purity: every read is written earlier in the same launch; outputs are a
// pure function of d_in. Cooperative path and fallback path compute
// bitwise-identical results (same per-element operation order).

// ==================== cooperative mega-kernel ====================
__global__ __launch_bounds__(256, 3) void fused_all(
    const float* __restrict__ z, const float* __restrict__ c,
    const float* __restrict__ Wk,
    const int* __restrict__ r1, const int* __restrict__ r2,
    const int* __restrict__ r3, const int* __restrict__ r4,
    const int* __restrict__ r5,
    float* __restrict__ out,
    unsigned short* __restrict__ Zp, unsigned short* __restrict__ Cb,
    unsigned short* __restrict__ Wb, unsigned short* __restrict__ Yb,
    float* __restrict__ Lk) {
  cg::grid_group grid = cg::this_grid();
  __shared__ __align__(16) char sm[9600];
  unsigned short* ctx = (unsigned short*)sm;        // 8448 B (score)
  float* L = (float*)(sm + 8448);                   // 1152 B (score)
  float (*tile)[33] = (float(*)[33])sm;             // 4224 B (transpose)
  float* red = (float*)sm;                          // 1024 B (total)

  const int bid = blockIdx.x;
  const int tid = threadIdx.x;
  const int wv = tid >> 6, lane = tid & 63;
  const int l15 = lane & 15, quad = lane >> 4;
  const int tx = tid & 31, ty = (tid >> 5) & 7;

  auto do_transpose_tile = [&](const float* in, unsigned short* outp,
                               int p0, int q0) {
#pragma unroll
    for (int r = 0; r < 32; r += 8)
      tile[ty + r][tx] = in[(size_t)(p0 + ty + r) * 256 + q0 + tx];
    __syncthreads();
#pragma unroll
    for (int r = 0; r < 32; r += 8)
      outp[(size_t)(q0 + ty + r) * 16384 + p0 + tx] = f2bu(tile[tx][ty + r]);
    __syncthreads();
  };

  // one 128-row M-tile of gemm step kk; loops 4 n-subtiles of 64
  auto do_gemm_mtile = [&](int kk, int mt) {
    const unsigned short* A = Zp + (size_t)(kk + 2) * 1024 * 256;
    const unsigned short* Wm = Wb + (size_t)kk * 65536;
    unsigned short* Y = Yb + (size_t)kk * 14336 * 256;
    const int m0w = mt * 128 + wv * 32;
    const unsigned short* a0 = A + (size_t)(m0w + l15) * 256 + quad * 8;
#pragma unroll
    for (int u = 0; u < 4; ++u) {
      const int n0 = u * 64;
      const unsigned short* b0 = Wm + (size_t)(n0 + l15) * 256 + quad * 8;
      f32x4 acc[2][4] = {};
#pragma unroll
      for (int ks = 0; ks < 8; ++ks) {
        bf16x8 a[2], b[4];
#pragma unroll
        for (int tm = 0; tm < 2; ++tm)
          a[tm] = *(const bf16x8*)(a0 + tm * 16 * 256 + ks * 32);
#pragma unroll
        for (int tn = 0; tn < 4; ++tn)
          b[tn] = *(const bf16x8*)(b0 + tn * 16 * 256 + ks * 32);
#pragma unroll
        for (int tm = 0; tm < 2; ++tm)
#pragma unroll
          for (int tn = 0; tn < 4; ++tn)
            acc[tm][tn] = __builtin_amdgcn_mfma_f32_16x16x32_bf16(
                a[tm], b[tn], acc[tm][tn], 0, 0, 0);
      }
#pragma unroll
      for (int tm = 0; tm < 2; ++tm)
#pragma unroll
        for (int tn = 0; tn < 4; ++tn)
#pragma unroll
          for (int r = 0; r < 4; ++r)
            Y[(size_t)(m0w + tm * 16 + quad * 4 + r) * 256 + n0 + tn * 16 + l15] =
                f2bu(acc[tm][tn][r]);
    }
  };

  // score group g2 of step kk (4 waves: chains 5/4/4/4)
  auto do_score = [&](int kk, int g2, const int* ridx) {
    const int Mk = (14 - kk) * 1024;
    const int m0 = g2 * 16;
    const unsigned short* Y = Yb + (size_t)kk * 14336 * 256;
    __syncthreads();   // protect LDS reuse across loop iterations
    {
      int u = tid;
      *(uint4*)(ctx + (u >> 5) * CTXW + (u & 31) * 8) =
          ((const uint4*)(Cb + (size_t)(m0 + (u >> 5)) * 256))[u & 31];
      u = tid + 256;
      *(uint4*)(ctx + (u >> 5) * CTXW + (u & 31) * 8) =
          ((const uint4*)(Cb + (size_t)(m0 + (u >> 5)) * 256))[u & 31];
    }
    __syncthreads();
    bf16x8 af[8];
#pragma unroll
    for (int tv = 0; tv < 8; ++tv)
      af[tv] = *(const bf16x8*)(ctx + l15 * CTXW + quad * 8 + tv * 32);

    const int c0 = (wv == 0) ? 0 : (4 * wv + 1);
    const int nc = (wv == 0) ? 5 : 4;
    const unsigned short* bp;
    if (c0 == 0) {
      bp = Y + (size_t)(m0 + l15) * 256 + quad * 8;
    } else {
      int idx = ridx[(m0 + (c0 - 1)) * NEG_ + l15];
      idx = idx < 0 ? 0 : (idx >= Mk ? Mk - 1 : idx);
      bp = Y + (size_t)idx * 256 + quad * 8;
    }
    bf16x8 bcur[8], bnxt[8];
#pragma unroll
    for (int tv = 0; tv < 8; ++tv) bcur[tv] = *(const bf16x8*)(bp + tv * 32);
    for (int j = 0; j < nc; ++j) {
      if (j + 1 < nc) {
        const int cc = c0 + j + 1;   // >=1 always
        int idx = ridx[(m0 + (cc - 1)) * NEG_ + l15];
        idx = idx < 0 ? 0 : (idx >= Mk ? Mk - 1 : idx);
        const unsigned short* np = Y + (size_t)idx * 256 + quad * 8;
#pragma unroll
        for (int tv = 0; tv < 8; ++tv) bnxt[tv] = *(const bf16x8*)(np + tv * 32);
      }
      f32x4 acc = {};
#pragma unroll
      for (int tv = 0; tv < 8; ++tv)
        acc = __builtin_amdgcn_mfma_f32_16x16x32_bf16(af[tv], bcur[tv], acc, 0, 0, 0);
      const int cc = c0 + j;
      if (cc == 0) {
#pragma unroll
        for (int r = 0; r < 4; ++r)
          if (l15 == quad * 4 + r) L[(quad * 4 + r) * LDW] = acc[r];
      } else {
        const int i = cc - 1;
        if (quad == (i >> 2)) L[i * LDW + 1 + l15] = acc[i & 3];
      }
#pragma unroll
      for (int tv = 0; tv < 8; ++tv) bcur[tv] = bnxt[tv];
    }
    __syncthreads();
    if (tid < 16) {
      float mainv = L[tid * LDW];
      float mx = mainv;
      float nv[NEG_];
#pragma unroll
      for (int n = 0; n < NEG_; ++n) {
        nv[n] = L[tid * LDW + 1 + n];
        mx = fmaxf(mx, nv[n]);
      }
      float num = __expf(mainv - mx);
      float se = num;
#pragma unroll
      for (int n = 0; n < NEG_; ++n) se += __expf(nv[n] - mx);
      Lk[kk * 14336 + m0 + tid] = -logf(num / se + EPS_);
    }
  };

  const int* rk[PRED_] = {r1, r2, r3, r4, r5};

  // ---- P0: W cast + z transpose ----
  for (int ii = bid; ii < 320; ii += GRID) {
    int i = ii * 256 + tid;
    float4 v = ((const float4*)Wk)[i];
    ushort4 o;
    o.x = f2bu(v.x); o.y = f2bu(v.y); o.z = f2bu(v.z); o.w = f2bu(v.w);
    ((ushort4*)Wb)[i] = o;
  }
  for (int t = bid; t < 3584; t += GRID)
    do_transpose_tile(z, Zp, (t & 511) * 32, ((t >> 9) << 5) + 32);
  grid.sync();

  // ---- P1: gemm(0) [112 blocks] || c transpose ----
  if (bid < 112) {
    do_gemm_mtile(0, bid);
  } else {
    for (int t = bid - 112; t < 3584; t += GRID - 112)
      do_transpose_tile(c, Cb, (t & 511) * 32, (t >> 9) << 5);
  }
  grid.sync();

  // ---- P2..P5: gemm(ph) || score(ph-1) ----
  for (int ph = 1; ph < PRED_; ++ph) {
    const int nb = (14 - ph) * 8;            // gemm M-tiles for step ph
    const int Gk = (15 - ph) * 64;           // score groups for step ph-1
    if (bid < nb) {
      do_gemm_mtile(ph, bid);
    } else {
      for (int g2 = bid - nb; g2 < Gk; g2 += GRID - nb)
        do_score(ph - 1, g2, rk[ph - 1]);
    }
    grid.sync();
  }

  // ---- P6: score(k=4) ----
  for (int g2 = bid; g2 < 640; g2 += GRID)
    do_score(4, g2, rk[4]);
  grid.sync();

  // ---- P7: patchwise loss + counts (blocks 0..63), total (block 64) ----
  if (bid < 64) {
    int idx = bid * 256 + tid;   // b*256 + h*16 + w
    int b = idx >> 8, h = (idx >> 4) & 15, w = idx & 15;
    float v = 0.f;
#pragma unroll
    for (int kk = 0; kk < PRED_; ++kk) {
      int off = kk + 2;
      if (h >= off)      v += Lk[kk * 14336 + ((h - off) * 16 + w) * 64 + b];
      if (h <= 15 - off) v += Lk[kk * 14336 + (h * 16 + w) * 64 + b];
    }
    out[1 + idx] = v;
    if (idx < 256) {
      int hh = idx >> 4;
      float cnt = 0.f;
#pragma unroll
      for (int off = 2; off <= 6; ++off)
        cnt += (hh >= off ? 1.f : 0.f) + (hh <= 15 - off ? 1.f : 0.f);
      out[1 + 16384 + idx] = cnt;
    }
  } else if (bid == 64) {
    float local = 0.f;
#pragma unroll
    for (int kk = 0; kk < PRED_; ++kk) {
      const int Mk = (14 - kk) * 1024;
      const float scale = 1.0f / (5120.0f * (float)(14 - kk));
      for (int e = tid; e < Mk; e += 256)
        local += Lk[kk * 14336 + e] * scale;
    }
    __syncthreads();
    red[tid] = local;
    __syncthreads();
    for (int s = 128; s; s >>= 1) {
      if (tid < s) red[tid] += red[tid + s];
      __syncthreads();
    }
    if (tid == 0) out[0] = red[0];
  }
}

// ==================== fallback path (proven R9 kernels) ====================
__global__ __launch_bounds__(256) void transpose_zc(
    const float* __restrict__ z, const float* __restrict__ c,
    unsigned short* __restrict__ Zp, unsigned short* __restrict__ Cb) {
  __shared__ float tile[32][33];
  const float* in = blockIdx.z ? c : z;
  unsigned short* out = blockIdx.z ? Cb : Zp;
  int p0 = blockIdx.x * 32;
  int q0 = blockIdx.y * 32 + (blockIdx.z ? 0 : 32);
  int tx = threadIdx.x, ty = threadIdx.y;
#pragma unroll
  for (int r = 0; r < 32; r += 8)
    tile[ty + r][tx] = in[(size_t)(p0 + ty + r) * 256 + q0 + tx];
  __syncthreads();
#pragma unroll
  for (int r = 0; r < 32; r += 8)
    out[(size_t)(q0 + ty + r) * 16384 + p0 + tx] = f2bu(tile[tx][ty + r]);
}

__global__ __launch_bounds__(256) void cast_w(
    const float* __restrict__ Wk, unsigned short* __restrict__ Wb) {
  int i = blockIdx.x * 256 + threadIdx.x;
  float4 v = ((const float4*)Wk)[i];
  ushort4 o;
  o.x = f2bu(v.x); o.y = f2bu(v.y); o.z = f2bu(v.z); o.w = f2bu(v.w);
  ((ushort4*)Wb)[i] = o;
}

__global__ __launch_bounds__(256) void gemm_fb(
    const unsigned short* __restrict__ Zp, const unsigned short* __restrict__ Wb,
    unsigned short* __restrict__ Yb) {
  const int kk = blockIdx.z;
  const int Mk = (14 - kk) * 1024;
  if (blockIdx.y * 128 >= Mk) return;
  const unsigned short* A = Zp + (size_t)(kk + 2) * 1024 * 256;
  const unsigned short* Wm = Wb + (size_t)kk * 65536;
  unsigned short* Y = Yb + (size_t)kk * 14336 * 256;
  const int wv = threadIdx.x >> 6, lane = threadIdx.x & 63;
  const int l15 = lane & 15, quad = lane >> 4;
  const int m0w = blockIdx.y * 128 + wv * 32;
  const unsigned short* a0 = A + (size_t)(m0w + l15) * 256 + quad * 8;
#pragma unroll
  for (int u = 0; u < 4; ++u) {
    const int n0 = u * 64;
    const unsigned short* b0 = Wm + (size_t)(n0 + l15) * 256 + quad * 8;
    f32x4 acc[2][4] = {};
#pragma unroll
    for (int ks = 0; ks < 8; ++ks) {
      bf16x8 a[2], b[4];
#pragma unroll
      for (int tm = 0; tm < 2; ++tm)
        a[tm] = *(const bf16x8*)(a0 + tm * 16 * 256 + ks * 32);
#pragma unroll
      for (int tn = 0; tn < 4; ++tn)
        b[tn] = *(const bf16x8*)(b0 + tn * 16 * 256 + ks * 32);
#pragma unroll
      for (int tm = 0; tm < 2; ++tm)
#pragma unroll
        for (int tn = 0; tn < 4; ++tn)
          acc[tm][tn] = __builtin_amdgcn_mfma_f32_16x16x32_bf16(
              a[tm], b[tn], acc[tm][tn], 0, 0, 0);
    }
#pragma unroll
    for (int tm = 0; tm < 2; ++tm)
#pragma unroll
      for (int tn = 0; tn < 4; ++tn)
#pragma unroll
        for (int r = 0; r < 4; ++r)
          Y[(size_t)(m0w + tm * 16 + quad * 4 + r) * 256 + n0 + tn * 16 + l15] =
              f2bu(acc[tm][tn][r]);
  }
}

__global__ __launch_bounds__(256) void score_fb(
    const unsigned short* __restrict__ Yb, const unsigned short* __restrict__ Cb,
    const int* __restrict__ r1, const int* __restrict__ r2,
    const int* __restrict__ r3, const int* __restrict__ r4,
    const int* __restrict__ r5, float* __restrict__ Lk) {
  __shared__ unsigned short ctx[16 * CTXW];
  __shared__ float L[16 * LDW];
  const int wv = threadIdx.x >> 6, lane = threadIdx.x & 63;
  const int gid = blockIdx.x;
  int kk, base;
  if (gid < 896)       { kk = 0; base = 0; }
  else if (gid < 1728) { kk = 1; base = 896; }
  else if (gid < 2496) { kk = 2; base = 1728; }
  else if (gid < 3200) { kk = 3; base = 2496; }
  else                 { kk = 4; base = 3200; }
  const int Mk = (14 - kk) * 1024;
  const int m0 = (gid - base) * 16;
  const int* ridx = kk == 0 ? r1 : kk == 1 ? r2 : kk == 2 ? r3 : kk == 3 ? r4 : r5;
  const unsigned short* Y = Yb + (size_t)kk * 14336 * 256;
  const int l15 = lane & 15, quad = lane >> 4;
  {
    int u = threadIdx.x;
    *(uint4*)(ctx + (u >> 5) * CTXW + (u & 31) * 8) =
        ((const uint4*)(Cb + (size_t)(m0 + (u >> 5)) * 256))[u & 31];
    u = threadIdx.x + 256;
    *(uint4*)(ctx + (u >> 5) * CTXW + (u & 31) * 8) =
        ((const uint4*)(Cb + (size_t)(m0 + (u >> 5)) * 256))[u & 31];
  }
  __syncthreads();
  bf16x8 af[8];
#pragma unroll
  for (int tv = 0; tv < 8; ++tv)
    af[tv] = *(const bf16x8*)(ctx + l15 * CTXW + quad * 8 + tv * 32);
  const int c0 = (wv == 0) ? 0 : (4 * wv + 1);
  const int nc = (wv == 0) ? 5 : 4;
  const unsigned short* bp;
  if (c0 == 0) {
    bp = Y + (size_t)(m0 + l15) * 256 + quad * 8;
  } else {
    int idx = ridx[(m0 + (c0 - 1)) * NEG_ + l15];
    idx = idx < 0 ? 0 : (idx >= Mk ? Mk - 1 : idx);
    bp = Y + (size_t)idx * 256 + quad * 8;
  }
  bf16x8 bcur[8], bnxt[8];
#pragma unroll
  for (int tv = 0; tv < 8; ++tv) bcur[tv] = *(const bf16x8*)(bp + tv * 32);
  for (int j = 0; j < nc; ++j) {
    if (j + 1 < nc) {
      const int cc = c0 + j + 1;
      int idx = ridx[(m0 + (cc - 1)) * NEG_ + l15];
      idx = idx < 0 ? 0 : (idx >= Mk ? Mk - 1 : idx);
      const unsigned short* np = Y + (size_t)idx * 256 + quad * 8;
#pragma unroll
      for (int tv = 0; tv < 8; ++tv) bnxt[tv] = *(const bf16x8*)(np + tv * 32);
    }
    f32x4 acc = {};
#pragma unroll
    for (int tv = 0; tv < 8; ++tv)
      acc = __builtin_amdgcn_mfma_f32_16x16x32_bf16(af[tv], bcur[tv], acc, 0, 0, 0);
    const int cc = c0 + j;
    if (cc == 0) {
#pragma unroll
      for (int r = 0; r < 4; ++r)
        if (l15 == quad * 4 + r) L[(quad * 4 + r) * LDW] = acc[r];
    } else {
      const int i = cc - 1;
      if (quad == (i >> 2)) L[i * LDW + 1 + l15] = acc[i & 3];
    }
#pragma unroll
    for (int tv = 0; tv < 8; ++tv) bcur[tv] = bnxt[tv];
  }
  __syncthreads();
  if (threadIdx.x < 16) {
    float mainv = L[threadIdx.x * LDW];
    float mx = mainv;
    float nv[NEG_];
#pragma unroll
    for (int n = 0; n < NEG_; ++n) {
      nv[n] = L[threadIdx.x * LDW + 1 + n];
      mx = fmaxf(mx, nv[n]);
    }
    float num = __expf(mainv - mx);
    float se = num;
#pragma unroll
    for (int n = 0; n < NEG_; ++n) se += __expf(nv[n] - mx);
    Lk[kk * 14336 + m0 + threadIdx.x] = -logf(num / se + EPS_);
  }
}

__global__ __launch_bounds__(1024) void total_fb(
    const float* __restrict__ Lk, float* __restrict__ out) {
  __shared__ float red[1024];
  const int t = threadIdx.x;
  float local = 0.f;
#pragma unroll
  for (int kk = 0; kk < PRED_; ++kk) {
    const int Mk = (14 - kk) * 1024;
    const float scale = 1.0f / (5120.0f * (float)(14 - kk));
    for (int e = t; e < Mk; e += 1024)
      local += Lk[kk * 14336 + e] * scale;
  }
  red[t] = local;
  __syncthreads();
  for (int s = 512; s; s >>= 1) {
    if (t < s) red[t] += red[t + s];
    __syncthreads();
  }
  if (t == 0) out[0] = red[0];
}

__global__ __launch_bounds__(256) void finalize_fb(
    const float* __restrict__ Lk, float* __restrict__ out) {
  int idx = blockIdx.x * 256 + threadIdx.x;
  int b = idx >> 8, h = (idx >> 4) & 15, w = idx & 15;
  float v = 0.f;
#pragma unroll
  for (int kk = 0; kk < PRED_; ++kk) {
    int off = kk + 2;
    if (h >= off)      v += Lk[kk * 14336 + ((h - off) * 16 + w) * 64 + b];
    if (h <= 15 - off) v += Lk[kk * 14336 + (h * 16 + w) * 64 + b];
  }
  out[1 + idx] = v;
  if (idx < 256) {
    int hh = idx >> 4;
    float cnt = 0.f;
#pragma unroll
    for (int off = 2; off <= 6; ++off)
      cnt += (hh >= off ? 1.f : 0.f) + (hh <= 15 - off ? 1.f : 0.f);
    out[1 + 16384 + idx] = cnt;
  }
}

extern "C" void kernel_launch(void* const* d_in, const int* in_sizes, int n_in,
                              void* d_out, int out_size, void* d_ws, size_t ws_size,
                              hipStream_t stream) {
  const float* z  = (const float*)d_in[0];
  const float* c  = (const float*)d_in[1];
  const float* Wk = (const float*)d_in[2];
  const int* r1 = (const int*)d_in[3];
  const int* r2 = (const int*)d_in[4];
  const int* r3 = (const int*)d_in[5];
  const int* r4 = (const int*)d_in[6];
  const int* r5 = (const int*)d_in[7];
  float* out = (float*)d_out;
  char* wsb = (char*)d_ws;
  unsigned short* Zp = (unsigned short*)(wsb);
  unsigned short* Cb = (unsigned short*)(wsb + 8388608);
  unsigned short* Wb = (unsigned short*)(wsb + 16777216);
  unsigned short* Yb = (unsigned short*)(wsb + 17432576);
  float*          Lk = (float*)(wsb + 54132736);

  void* args[] = {&z, &c, &Wk, &r1, &r2, &r3, &r4, &r5,
                  &out, &Zp, &Cb, &Wb, &Yb, &Lk};
  hipError_t rc = hipLaunchCooperativeKernel(
      (const void*)fused_all, dim3(GRID), dim3(256), args, 0, stream);
  if (rc != hipSuccess) {
    (void)hipGetLastError();   // clear error; take proven multi-kernel path
    transpose_zc<<<dim3(512, 7, 2), dim3(32, 8), 0, stream>>>(z, c, Zp, Cb);
    cast_w<<<320, 256, 0, stream>>>(Wk, Wb);
    gemm_fb<<<dim3(1, 112, PRED_), 256, 0, stream>>>(Zp, Wb, Yb);
    score_fb<<<3840, 256, 0, stream>>>(Yb, Cb, r1, r2, r3, r4, r5, Lk);
    finalize_fb<<<64, 256, 0, stream>>>(Lk, out);
    total_fb<<<1, 1024, 0, stream>>>(Lk, out);
  }
}

// Round 12
// 193.218 us; speedup vs baseline: 4.7923x; 4.7923x over previous
//
#include <hip/hip_runtime.h>
#include <hip/hip_bf16.h>
#include <math.h>

#define NEG_ 16
#define PRED_ 5
#define EPS_ 1e-11f
#define LDW 18    // logit tile row stride (floats)
#define GSTR 272  // LDS gather-row stride in shorts (544 B): balanced bank groups

typedef __attribute__((ext_vector_type(8))) short bf16x8;
typedef __attribute__((ext_vector_type(4))) float f32x4;

static __device__ __forceinline__ unsigned short f2bu(float f) {
  __hip_bfloat16 h = __float2bfloat16(f);
  return *(unsigned short*)&h;
}

// ws layout (bytes):
//   Zp bf16 [16384][256] : 0         rows q*64+b; rows<2048 (h<2) never touched
//   Cb bf16 [16384][256] : 8388608   rows>=14336 never touched
//   Wb bf16 [5][256][256]: 16777216
//   Yb bf16 [5][14336][256]: 17432576  rows>=Mk unused per k
//   Lk f32  [5][14336]   : 54132736  tails [Mk,14336) NEVER read -> no memset
// Purity: every read is of data written earlier in this launch.

// ---- prep: transpose z/c (+cast) and cast W, one dispatch ----
// grid (512, 8, 2), block (32,8). by<7: transpose; (by==7,bz==0): W cast.
__global__ __launch_bounds__(256) void prep_all(
    const float* __restrict__ z, const float* __restrict__ c,
    const float* __restrict__ Wk,
    unsigned short* __restrict__ Zp, unsigned short* __restrict__ Cb,
    unsigned short* __restrict__ Wb) {
  __shared__ float tile[32][33];
  int tx = threadIdx.x, ty = threadIdx.y;
  if (blockIdx.y == 7) {
    if (blockIdx.z == 0 && blockIdx.x < 320) {
      int i = blockIdx.x * 256 + ty * 32 + tx;
      float4 v = ((const float4*)Wk)[i];
      ushort4 o;
      o.x = f2bu(v.x); o.y = f2bu(v.y); o.z = f2bu(v.z); o.w = f2bu(v.w);
      ((ushort4*)Wb)[i] = o;
    }
    return;
  }
  const float* in = blockIdx.z ? c : z;
  unsigned short* out = blockIdx.z ? Cb : Zp;
  int p0 = blockIdx.x * 32;                          // [0,16384)
  int q0 = blockIdx.y * 32 + (blockIdx.z ? 0 : 32);  // z:[32,256) c:[0,224)
#pragma unroll
  for (int r = 0; r < 32; r += 8)
    tile[ty + r][tx] = in[(size_t)(p0 + ty + r) * 256 + q0 + tx];
  __syncthreads();
#pragma unroll
  for (int r = 0; r < 32; r += 8)
    out[(size_t)(q0 + ty + r) * 16384 + p0 + tx] = f2bu(tile[tx][ty + r]);
}

// ---- batched MFMA GEMM, register-double-buffered K loop (R8, proven) ----
__global__ __launch_bounds__(256) void gemm_all(
    const unsigned short* __restrict__ Zp, const unsigned short* __restrict__ Wb,
    unsigned short* __restrict__ Yb) {
  const int kk = blockIdx.z;
  const int Mk = (14 - kk) * 1024;
  const int m0b = blockIdx.y * 128;
  if (m0b >= Mk) return;
  const unsigned short* A = Zp + (size_t)(kk + 2) * 1024 * 256;
  const unsigned short* Wm = Wb + (size_t)kk * 65536;
  unsigned short* Y = Yb + (size_t)kk * 14336 * 256;
  const int t = threadIdx.x;
  const int wid = t >> 6, lane = t & 63;
  const int wm = wid >> 1, wn = wid & 1;
  const int l15 = lane & 15, quad = lane >> 4;
  const int m0 = m0b + wm * 64;
  const int n0 = blockIdx.x * 128 + wn * 64;
  const unsigned short* a0 = A + (size_t)(m0 + l15) * 256 + quad * 8;
  const unsigned short* b0 = Wm + (size_t)(n0 + l15) * 256 + quad * 8;
  f32x4 acc[4][4] = {};
  bf16x8 ac[4], bc[4], an[4], bn[4];
#pragma unroll
  for (int tm = 0; tm < 4; ++tm) ac[tm] = *(const bf16x8*)(a0 + tm * 16 * 256);
#pragma unroll
  for (int tn = 0; tn < 4; ++tn) bc[tn] = *(const bf16x8*)(b0 + tn * 16 * 256);
#pragma unroll
  for (int kb = 0; kb < 8; ++kb) {
    if (kb < 7) {
      const int k1 = (kb + 1) * 32;
#pragma unroll
      for (int tm = 0; tm < 4; ++tm) an[tm] = *(const bf16x8*)(a0 + tm * 16 * 256 + k1);
#pragma unroll
      for (int tn = 0; tn < 4; ++tn) bn[tn] = *(const bf16x8*)(b0 + tn * 16 * 256 + k1);
    }
#pragma unroll
    for (int tm = 0; tm < 4; ++tm)
#pragma unroll
      for (int tn = 0; tn < 4; ++tn)
        acc[tm][tn] = __builtin_amdgcn_mfma_f32_16x16x32_bf16(ac[tm], bc[tn], acc[tm][tn], 0, 0, 0);
#pragma unroll
    for (int tm = 0; tm < 4; ++tm) ac[tm] = an[tm];
#pragma unroll
    for (int tn = 0; tn < 4; ++tn) bc[tn] = bn[tn];
  }
#pragma unroll
  for (int tm = 0; tm < 4; ++tm)
#pragma unroll
    for (int tn = 0; tn < 4; ++tn)
#pragma unroll
      for (int r = 0; r < 4; ++r)
        Y[(size_t)(m0 + tm * 16 + quad * 4 + r) * 256 + n0 + tn * 16 + l15] =
            f2bu(acc[tm][tn][r]);
}

// ---- fused scoring: ALL global loads wave-contiguous ----
// One block (4 waves) per 16-row group; chains split 5/4/4/4. Each chain's
// 16 rows (512 B each) are fetched as 8 coalesced 1KB instructions (2 rows
// per instr, 16B/lane), staged in a wave-private padded LDS buffer, then
// read back in MFMA B-fragment layout. ctx/af uses the same path once.
__global__ __launch_bounds__(256) void score_all(
    const unsigned short* __restrict__ Yb, const unsigned short* __restrict__ Cb,
    const int* __restrict__ r1, const int* __restrict__ r2,
    const int* __restrict__ r3, const int* __restrict__ r4,
    const int* __restrict__ r5, float* __restrict__ Lk) {
  __shared__ __align__(16) unsigned short gbuf[4][16 * GSTR];  // 4 x 8704 B
  __shared__ float L[16 * LDW];
  const int wv = threadIdx.x >> 6, lane = threadIdx.x & 63;
  const int gid = blockIdx.x;   // 0..3839
  int kk, base;
  if (gid < 896)       { kk = 0; base = 0; }
  else if (gid < 1728) { kk = 1; base = 896; }
  else if (gid < 2496) { kk = 2; base = 1728; }
  else if (gid < 3200) { kk = 3; base = 2496; }
  else                 { kk = 4; base = 3200; }
  const int Mk = (14 - kk) * 1024;
  const int m0 = (gid - base) * 16;
  const int* ridx = kk == 0 ? r1 : kk == 1 ? r2 : kk == 2 ? r3 : kk == 3 ? r4 : r5;
  const unsigned short* Y = Yb + (size_t)kk * 14336 * 256;
  const int l15 = lane & 15, quad = lane >> 4;
  const int half = lane >> 5, ch = lane & 31;   // row-pair half, 16B chunk
  unsigned short* mybuf = gbuf[wv];

  // coalesced gather of 16 rows (indices in iv, one per l15) from src
  auto gather = [&](const unsigned short* src, int iv, bf16x8* dst) {
#pragma unroll
    for (int j = 0; j < 8; ++j) {
      int rlo = __shfl(iv, 2 * j);
      int rhi = __shfl(iv, 2 * j + 1);
      int row = half ? rhi : rlo;
      dst[j] = *(const bf16x8*)(src + (size_t)row * 256 + ch * 8);
    }
  };
  auto stage = [&](const bf16x8* g) {
#pragma unroll
    for (int j2 = 0; j2 < 8; ++j2)
      *(bf16x8*)(mybuf + (2 * j2 + half) * GSTR + ch * 8) = g[j2];
  };

  // --- af fragments: ctx rows m0..m0+15 via coalesced path ---
  bf16x8 af[8];
  {
    bf16x8 g[8];
    gather(Cb, m0 + l15, g);
    stage(g);
#pragma unroll
    for (int tv = 0; tv < 8; ++tv)
      af[tv] = *(const bf16x8*)(mybuf + l15 * GSTR + quad * 8 + tv * 32);
  }

  // chain c: 0 = main (rows m0..m0+15 of Y), c>=1 = neg i=c-1 (gathered)
  const int c0 = (wv == 0) ? 0 : (4 * wv + 1);
  const int nc = (wv == 0) ? 5 : 4;
  auto load_iv = [&](int c) -> int {
    if (c == 0) return m0 + l15;
    int idx = ridx[(m0 + (c - 1)) * NEG_ + l15];
    return idx < 0 ? 0 : (idx >= Mk ? Mk - 1 : idx);
  };

  bf16x8 g[8], gn[8];
  gather(Y, load_iv(c0), g);
  for (int j = 0; j < nc; ++j) {
    if (j + 1 < nc) gather(Y, load_iv(c0 + j + 1), gn);
    stage(g);
    f32x4 acc = {};
#pragma unroll
    for (int tv = 0; tv < 8; ++tv) {
      bf16x8 bf = *(const bf16x8*)(mybuf + l15 * GSTR + quad * 8 + tv * 32);
      acc = __builtin_amdgcn_mfma_f32_16x16x32_bf16(af[tv], bf, acc, 0, 0, 0);
    }
    const int c = c0 + j;
    if (c == 0) {
#pragma unroll
      for (int r = 0; r < 4; ++r)
        if (l15 == quad * 4 + r) L[(quad * 4 + r) * LDW] = acc[r];
    } else {
      const int i = c - 1;
      if (quad == (i >> 2)) L[i * LDW + 1 + l15] = acc[i & 3];
    }
#pragma unroll
    for (int tv = 0; tv < 8; ++tv) g[tv] = gn[tv];
  }
  __syncthreads();
  if (threadIdx.x < 16) {
    float mainv = L[threadIdx.x * LDW];
    float mx = mainv;
    float nv[NEG_];
#pragma unroll
    for (int n = 0; n < NEG_; ++n) {
      nv[n] = L[threadIdx.x * LDW + 1 + n];
      mx = fmaxf(mx, nv[n]);
    }
    float num = __expf(mainv - mx);
    float se = num;
#pragma unroll
    for (int n = 0; n < NEG_; ++n) se += __expf(nv[n] - mx);
    Lk[kk * 14336 + m0 + threadIdx.x] = -logf(num / se + EPS_);
  }
}

// ---- total loss: one block, sums only valid rows [0,Mk) per k ----
__global__ __launch_bounds__(1024) void total_all(
    const float* __restrict__ Lk, float* __restrict__ out) {
  __shared__ float red[1024];
  const int t = threadIdx.x;
  float local = 0.f;
#pragma unroll
  for (int kk = 0; kk < PRED_; ++kk) {
    const int Mk = (14 - kk) * 1024;
    const float scale = 1.0f / (5120.0f * (float)(14 - kk));
    for (int e = t; e < Mk; e += 1024)
      local += Lk[kk * 14336 + e] * scale;
  }
  red[t] = local;
  __syncthreads();
  for (int s = 512; s; s >>= 1) {
    if (t < s) red[t] += red[t + s];
    __syncthreads();
  }
  if (t == 0) out[0] = red[0];
}

// ---- patchwise loss + counts (pure gather, each out element written once) ----
__global__ __launch_bounds__(256) void finalize_pl(
    const float* __restrict__ Lk, float* __restrict__ out) {
  int idx = blockIdx.x * 256 + threadIdx.x;   // b*256 + h*16 + w
  int b = idx >> 8, h = (idx >> 4) & 15, w = idx & 15;
  float v = 0.f;
#pragma unroll
  for (int kk = 0; kk < PRED_; ++kk) {
    int off = kk + 2;
    if (h >= off)      v += Lk[kk * 14336 + ((h - off) * 16 + w) * 64 + b];
    if (h <= 15 - off) v += Lk[kk * 14336 + (h * 16 + w) * 64 + b];
  }
  out[1 + idx] = v;
  if (idx < 256) {
    int hh = idx >> 4;
    float cnt = 0.f;
#pragma unroll
    for (int off = 2; off <= 6; ++off)
      cnt += (hh >= off ? 1.f : 0.f) + (hh <= 15 - off ? 1.f : 0.f);
    out[1 + 16384 + idx] = cnt;
  }
}

extern "C" void kernel_launch(void* const* d_in, const int* in_sizes, int n_in,
                              void* d_out, int out_size, void* d_ws, size_t ws_size,
                              hipStream_t stream) {
  const float* z  = (const float*)d_in[0];
  const float* c  = (const float*)d_in[1];
  const float* Wk = (const float*)d_in[2];
  float* out = (float*)d_out;
  char* wsb = (char*)d_ws;
  unsigned short* Zp = (unsigned short*)(wsb);
  unsigned short* Cb = (unsigned short*)(wsb + 8388608);
  unsigned short* Wb = (unsigned short*)(wsb + 16777216);
  unsigned short* Yb = (unsigned short*)(wsb + 17432576);
  float*          Lk = (float*)(wsb + 54132736);

  prep_all<<<dim3(512, 8, 2), dim3(32, 8), 0, stream>>>(z, c, Wk, Zp, Cb, Wb);
  gemm_all<<<dim3(2, 112, PRED_), 256, 0, stream>>>(Zp, Wb, Yb);
  score_all<<<3840, 256, 0, stream>>>(
      Yb, Cb, (const int*)d_in[3], (const int*)d_in[4], (const int*)d_in[5],
      (const int*)d_in[6], (const int*)d_in[7], Lk);
  finalize_pl<<<64, 256, 0, stream>>>(Lk, out);
  total_all<<<1, 1024, 0, stream>>>(Lk, out);
}

// Round 13
// 185.522 us; speedup vs baseline: 4.9911x; 1.0415x over previous
//
#include <hip/hip_runtime.h>
#include <hip/hip_bf16.h>
#include <math.h>

#define NEG_ 16
#define PRED_ 5
#define EPS_ 1e-11f
#define LDW 18    // logit tile row stride (floats)
#define GSTR 272  // score LDS gather-row stride in shorts (544 B)
#define ASTR 72   // gemm LDS tile row stride in shorts (144 B, 16B-aligned)

typedef __attribute__((ext_vector_type(8))) short bf16x8;
typedef __attribute__((ext_vector_type(4))) float f32x4;

static __device__ __forceinline__ unsigned short f2bu(float f) {
  __hip_bfloat16 h = __float2bfloat16(f);
  return *(unsigned short*)&h;
}

// ws layout (bytes):
//   Zp bf16 [16384][256] : 0         rows q*64+b; rows<2048 (h<2) never touched
//   Cb bf16 [16384][256] : 8388608   rows>=14336 never touched
//   Wb bf16 [5][256][256]: 16777216
//   Yb bf16 [5][14336][256]: 17432576  rows>=Mk unused per k
//   Lk f32  [5][14336]   : 54132736  tails [Mk,14336) NEVER read -> no memset
// Purity: every read is of data written earlier in this launch.

// ---- prep: transpose z/c (+cast) and cast W, one dispatch ----
__global__ __launch_bounds__(256) void prep_all(
    const float* __restrict__ z, const float* __restrict__ c,
    const float* __restrict__ Wk,
    unsigned short* __restrict__ Zp, unsigned short* __restrict__ Cb,
    unsigned short* __restrict__ Wb) {
  __shared__ float tile[32][33];
  int tx = threadIdx.x, ty = threadIdx.y;
  if (blockIdx.y == 7) {
    if (blockIdx.z == 0 && blockIdx.x < 320) {
      int i = blockIdx.x * 256 + ty * 32 + tx;
      float4 v = ((const float4*)Wk)[i];
      ushort4 o;
      o.x = f2bu(v.x); o.y = f2bu(v.y); o.z = f2bu(v.z); o.w = f2bu(v.w);
      ((ushort4*)Wb)[i] = o;
    }
    return;
  }
  const float* in = blockIdx.z ? c : z;
  unsigned short* out = blockIdx.z ? Cb : Zp;
  int p0 = blockIdx.x * 32;
  int q0 = blockIdx.y * 32 + (blockIdx.z ? 0 : 32);
#pragma unroll
  for (int r = 0; r < 32; r += 8)
    tile[ty + r][tx] = in[(size_t)(p0 + ty + r) * 256 + q0 + tx];
  __syncthreads();
#pragma unroll
  for (int r = 0; r < 32; r += 8)
    out[(size_t)(q0 + ty + r) * 16384 + p0 + tx] = f2bu(tile[tx][ty + r]);
}

// ---- LDS-staged MFMA GEMM: 128x128 tile, BK=64, coalesced staging ----
__global__ __launch_bounds__(256) void gemm_all(
    const unsigned short* __restrict__ Zp, const unsigned short* __restrict__ Wb,
    unsigned short* __restrict__ Yb) {
  const int kk = blockIdx.z;
  const int Mk = (14 - kk) * 1024;
  const int m0b = blockIdx.y * 128;
  if (m0b >= Mk) return;
  const unsigned short* A = Zp + (size_t)(kk + 2) * 1024 * 256;
  const unsigned short* Wm = Wb + (size_t)kk * 65536;
  unsigned short* Y = Yb + (size_t)kk * 14336 * 256;
  __shared__ unsigned short As[128 * ASTR];   // 18432 B
  __shared__ unsigned short Bs[128 * ASTR];   // 18432 B
  const int t = threadIdx.x;
  const int wid = t >> 6, lane = t & 63;
  const int wm = wid >> 1, wn = wid & 1;
  const int l15 = lane & 15, quad = lane >> 4;
  const int n0 = blockIdx.x * 128;
  // staging: thread t covers row t>>1, 64B half (t&1) of each 128B k-slab
  const int srow = t >> 1, shalf = t & 1;
  const unsigned short* ga = A + (size_t)(m0b + srow) * 256 + shalf * 32;
  const unsigned short* gb = Wm + (size_t)(n0 + srow) * 256 + shalf * 32;
  unsigned short* wa = As + srow * ASTR + shalf * 32;
  unsigned short* wb = Bs + srow * ASTR + shalf * 32;
  f32x4 acc[4][4] = {};
  bf16x8 ra[4], rb[4];
#pragma unroll
  for (int cs = 0; cs < 4; ++cs) {
    ra[cs] = *(const bf16x8*)(ga + cs * 8);
    rb[cs] = *(const bf16x8*)(gb + cs * 8);
  }
#pragma unroll
  for (int ki = 0; ki < 4; ++ki) {
    __syncthreads();
#pragma unroll
    for (int cs = 0; cs < 4; ++cs) {
      *(bf16x8*)(wa + cs * 8) = ra[cs];
      *(bf16x8*)(wb + cs * 8) = rb[cs];
    }
    __syncthreads();
    if (ki < 3) {
      const int k1 = (ki + 1) * 64;
#pragma unroll
      for (int cs = 0; cs < 4; ++cs) {
        ra[cs] = *(const bf16x8*)(ga + k1 + cs * 8);
        rb[cs] = *(const bf16x8*)(gb + k1 + cs * 8);
      }
    }
#pragma unroll
    for (int ks = 0; ks < 2; ++ks) {
      bf16x8 af[4], bf[4];
#pragma unroll
      for (int tm = 0; tm < 4; ++tm)
        af[tm] = *(const bf16x8*)(As + (wm * 64 + tm * 16 + l15) * ASTR + ks * 32 + quad * 8);
#pragma unroll
      for (int tn = 0; tn < 4; ++tn)
        bf[tn] = *(const bf16x8*)(Bs + (wn * 64 + tn * 16 + l15) * ASTR + ks * 32 + quad * 8);
#pragma unroll
      for (int tm = 0; tm < 4; ++tm)
#pragma unroll
        for (int tn = 0; tn < 4; ++tn)
          acc[tm][tn] = __builtin_amdgcn_mfma_f32_16x16x32_bf16(
              af[tm], bf[tn], acc[tm][tn], 0, 0, 0);
    }
  }
#pragma unroll
  for (int tm = 0; tm < 4; ++tm)
#pragma unroll
    for (int tn = 0; tn < 4; ++tn)
#pragma unroll
      for (int r = 0; r < 4; ++r)
        Y[(size_t)(m0b + wm * 64 + tm * 16 + quad * 4 + r) * 256 +
          n0 + wn * 64 + tn * 16 + l15] = f2bu(acc[tm][tn][r]);
}

// ---- fused scoring (R12, proven): all global loads wave-contiguous ----
__global__ __launch_bounds__(256) void score_all(
    const unsigned short* __restrict__ Yb, const unsigned short* __restrict__ Cb,
    const int* __restrict__ r1, const int* __restrict__ r2,
    const int* __restrict__ r3, const int* __restrict__ r4,
    const int* __restrict__ r5, float* __restrict__ Lk) {
  __shared__ __align__(16) unsigned short gbuf[4][16 * GSTR];
  __shared__ float L[16 * LDW];
  const int wv = threadIdx.x >> 6, lane = threadIdx.x & 63;
  const int gid = blockIdx.x;
  int kk, base;
  if (gid < 896)       { kk = 0; base = 0; }
  else if (gid < 1728) { kk = 1; base = 896; }
  else if (gid < 2496) { kk = 2; base = 1728; }
  else if (gid < 3200) { kk = 3; base = 2496; }
  else                 { kk = 4; base = 3200; }
  const int Mk = (14 - kk) * 1024;
  const int m0 = (gid - base) * 16;
  const int* ridx = kk == 0 ? r1 : kk == 1 ? r2 : kk == 2 ? r3 : kk == 3 ? r4 : r5;
  const unsigned short* Y = Yb + (size_t)kk * 14336 * 256;
  const int l15 = lane & 15, quad = lane >> 4;
  const int half = lane >> 5, ch = lane & 31;
  unsigned short* mybuf = gbuf[wv];

  auto gather = [&](const unsigned short* src, int iv, bf16x8* dst) {
#pragma unroll
    for (int j = 0; j < 8; ++j) {
      int rlo = __shfl(iv, 2 * j);
      int rhi = __shfl(iv, 2 * j + 1);
      int row = half ? rhi : rlo;
      dst[j] = *(const bf16x8*)(src + (size_t)row * 256 + ch * 8);
    }
  };
  auto stage = [&](const bf16x8* g) {
#pragma unroll
    for (int j2 = 0; j2 < 8; ++j2)
      *(bf16x8*)(mybuf + (2 * j2 + half) * GSTR + ch * 8) = g[j2];
  };

  bf16x8 af[8];
  {
    bf16x8 g[8];
    gather(Cb, m0 + l15, g);
    stage(g);
#pragma unroll
    for (int tv = 0; tv < 8; ++tv)
      af[tv] = *(const bf16x8*)(mybuf + l15 * GSTR + quad * 8 + tv * 32);
  }

  const int c0 = (wv == 0) ? 0 : (4 * wv + 1);
  const int nc = (wv == 0) ? 5 : 4;
  auto load_iv = [&](int c) -> int {
    if (c == 0) return m0 + l15;
    int idx = ridx[(m0 + (c - 1)) * NEG_ + l15];
    return idx < 0 ? 0 : (idx >= Mk ? Mk - 1 : idx);
  };

  bf16x8 g[8], gn[8];
  gather(Y, load_iv(c0), g);
  for (int j = 0; j < nc; ++j) {
    if (j + 1 < nc) gather(Y, load_iv(c0 + j + 1), gn);
    stage(g);
    f32x4 acc = {};
#pragma unroll
    for (int tv = 0; tv < 8; ++tv) {
      bf16x8 bf = *(const bf16x8*)(mybuf + l15 * GSTR + quad * 8 + tv * 32);
      acc = __builtin_amdgcn_mfma_f32_16x16x32_bf16(af[tv], bf, acc, 0, 0, 0);
    }
    const int c = c0 + j;
    if (c == 0) {
#pragma unroll
      for (int r = 0; r < 4; ++r)
        if (l15 == quad * 4 + r) L[(quad * 4 + r) * LDW] = acc[r];
    } else {
      const int i = c - 1;
      if (quad == (i >> 2)) L[i * LDW + 1 + l15] = acc[i & 3];
    }
#pragma unroll
    for (int tv = 0; tv < 8; ++tv) g[tv] = gn[tv];
  }
  __syncthreads();
  if (threadIdx.x < 16) {
    float mainv = L[threadIdx.x * LDW];
    float mx = mainv;
    float nv[NEG_];
#pragma unroll
    for (int n = 0; n < NEG_; ++n) {
      nv[n] = L[threadIdx.x * LDW + 1 + n];
      mx = fmaxf(mx, nv[n]);
    }
    float num = __expf(mainv - mx);
    float se = num;
#pragma unroll
    for (int n = 0; n < NEG_; ++n) se += __expf(nv[n] - mx);
    Lk[kk * 14336 + m0 + threadIdx.x] = -logf(num / se + EPS_);
  }
}

// ---- patchwise loss + counts (blocks 0..63) + total (block 64) ----
__global__ __launch_bounds__(256) void finalize_pl(
    const float* __restrict__ Lk, float* __restrict__ out) {
  if (blockIdx.x < 64) {
    int idx = blockIdx.x * 256 + threadIdx.x;   // b*256 + h*16 + w
    int b = idx >> 8, h = (idx >> 4) & 15, w = idx & 15;
    float v = 0.f;
#pragma unroll
    for (int kk = 0; kk < PRED_; ++kk) {
      int off = kk + 2;
      if (h >= off)      v += Lk[kk * 14336 + ((h - off) * 16 + w) * 64 + b];
      if (h <= 15 - off) v += Lk[kk * 14336 + (h * 16 + w) * 64 + b];
    }
    out[1 + idx] = v;
    if (idx < 256) {
      int hh = idx >> 4;
      float cnt = 0.f;
#pragma unroll
      for (int off = 2; off <= 6; ++off)
        cnt += (hh >= off ? 1.f : 0.f) + (hh <= 15 - off ? 1.f : 0.f);
      out[1 + 16384 + idx] = cnt;
    }
  } else {
    __shared__ float red[256];
    const int t = threadIdx.x;
    float local = 0.f;
#pragma unroll
    for (int kk = 0; kk < PRED_; ++kk) {
      const int Mk = (14 - kk) * 1024;
      const float scale = 1.0f / (5120.0f * (float)(14 - kk));
      for (int e = t; e < Mk; e += 256)
        local += Lk[kk * 14336 + e] * scale;
    }
    red[t] = local;
    __syncthreads();
    for (int s = 128; s; s >>= 1) {
      if (t < s) red[t] += red[t + s];
      __syncthreads();
    }
    if (t == 0) out[0] = red[0];
  }
}

extern "C" void kernel_launch(void* const* d_in, const int* in_sizes, int n_in,
                              void* d_out, int out_size, void* d_ws, size_t ws_size,
                              hipStream_t stream) {
  const float* z  = (const float*)d_in[0];
  const float* c  = (const float*)d_in[1];
  const float* Wk = (const float*)d_in[2];
  float* out = (float*)d_out;
  char* wsb = (char*)d_ws;
  unsigned short* Zp = (unsigned short*)(wsb);
  unsigned short* Cb = (unsigned short*)(wsb + 8388608);
  unsigned short* Wb = (unsigned short*)(wsb + 16777216);
  unsigned short* Yb = (unsigned short*)(wsb + 17432576);
  float*          Lk = (float*)(wsb + 54132736);

  prep_all<<<dim3(512, 8, 2), dim3(32, 8), 0, stream>>>(z, c, Wk, Zp, Cb, Wb);
  gemm_all<<<dim3(2, 112, PRED_), 256, 0, stream>>>(Zp, Wb, Yb);
  score_all<<<3840, 256, 0, stream>>>(
      Yb, Cb, (const int*)d_in[3], (const int*)d_in[4], (const int*)d_in[5],
      (const int*)d_in[6], (const int*)d_in[7], Lk);
  finalize_pl<<<65, 256, 0, stream>>>(Lk, out);
}